// Round 6
// baseline (230.296 us; speedup 1.0000x reference)
//
#include <hip/hip_runtime.h>
#include <stdint.h>

typedef _Float16 half8 __attribute__((ext_vector_type(8)));
typedef float floatx4 __attribute__((ext_vector_type(4)));
typedef float fvec4 __attribute__((ext_vector_type(4)));

struct WPtrs { const float *wc, *wn, *wp, *we; };

// ---------------------------------------------------------------------------
// pack one (node,slot) of nei_p/nei_e into the fp16 pe row
// layout per slot: [p0,p1,p2,0, e0..e7, 0,0,0,0], each part L2-normalized
// Streaming data -> nontemporal loads/stores (keep L2 for xhat gathers).
// ---------------------------------------------------------------------------
template <int D, int PEP>
__device__ inline void pack_pe_one(const float* __restrict__ p,
                                   const float* __restrict__ e,
                                   _Float16* __restrict__ pe, int idx) {
  int node = idx / D;
  int slot = idx % D;

  const float* pp = p + (size_t)idx * 3;
  float p0 = __builtin_nontemporal_load(pp + 0);
  float p1 = __builtin_nontemporal_load(pp + 1);
  float p2 = __builtin_nontemporal_load(pp + 2);
  float pn = sqrtf(p0 * p0 + p1 * p1 + p2 * p2);
  float rp = pn > 0.f ? 1.f / pn : 0.f;

  const fvec4* ee = reinterpret_cast<const fvec4*>(e + (size_t)idx * 8);
  fvec4 e0 = __builtin_nontemporal_load(ee);
  fvec4 e1 = __builtin_nontemporal_load(ee + 1);
  float en = sqrtf(e0[0] * e0[0] + e0[1] * e0[1] + e0[2] * e0[2] + e0[3] * e0[3] +
                   e1[0] * e1[0] + e1[1] * e1[1] + e1[2] * e1[2] + e1[3] * e1[3]);
  float re = en > 0.f ? 1.f / en : 0.f;

  half8 h0, h1;
  h0[0] = (_Float16)(p0 * rp); h0[1] = (_Float16)(p1 * rp);
  h0[2] = (_Float16)(p2 * rp); h0[3] = (_Float16)0.f;
  h0[4] = (_Float16)(e0[0] * re); h0[5] = (_Float16)(e0[1] * re);
  h0[6] = (_Float16)(e0[2] * re); h0[7] = (_Float16)(e0[3] * re);
  h1[0] = (_Float16)(e1[0] * re); h1[1] = (_Float16)(e1[1] * re);
  h1[2] = (_Float16)(e1[2] * re); h1[3] = (_Float16)(e1[3] * re);
  h1[4] = (_Float16)0.f; h1[5] = (_Float16)0.f;
  h1[6] = (_Float16)0.f; h1[7] = (_Float16)0.f;

  _Float16* dst = pe + (size_t)node * PEP + slot * 16;
  __builtin_nontemporal_store(h0, reinterpret_cast<half8*>(dst));
  __builtin_nontemporal_store(h1, reinterpret_cast<half8*>(dst + 8));

  half8 z = {};
  if (D == 1) {  // pad [16,32)
    _Float16* pz = pe + (size_t)node * PEP + 16;
    __builtin_nontemporal_store(z, reinterpret_cast<half8*>(pz));
    __builtin_nontemporal_store(z, reinterpret_cast<half8*>(pz + 8));
  }
  if (D == 3 && slot == 0) {  // pad [48,64)
    _Float16* pz = pe + (size_t)node * PEP + 48;
    __builtin_nontemporal_store(z, reinterpret_cast<half8*>(pz));
    __builtin_nontemporal_store(z, reinterpret_cast<half8*>(pz + 8));
  }
}

// ---------------------------------------------------------------------------
// Fused prep kernel: grid = [norm blocks | pe blocks | 4 weight blocks]
// ---------------------------------------------------------------------------
struct PrepArgs {
  const float* x; _Float16* xhat; int N; int nb_norm;
  const float* p[4]; const float* e[4]; _Float16* pe[4];
  int slotOff[5]; int nb_pe;
  WPtrs w[4]; _Float16* psi;
};

__global__ __launch_bounds__(256) void k_prep(PrepArgs a) {
  int bid = blockIdx.x, tid = threadIdx.x;

  if (bid < a.nb_norm) {
    // ---- normalize x rows: 4 lanes per row ----
    int row = bid * 64 + (tid >> 2);
    int q   = tid & 3;
    if (row >= a.N) return;
    const fvec4* xr = reinterpret_cast<const fvec4*>(a.x + (size_t)row * 32 + q * 8);
    fvec4 va = __builtin_nontemporal_load(xr);
    fvec4 vb = __builtin_nontemporal_load(xr + 1);
    float ss = va[0] * va[0] + va[1] * va[1] + va[2] * va[2] + va[3] * va[3] +
               vb[0] * vb[0] + vb[1] * vb[1] + vb[2] * vb[2] + vb[3] * vb[3];
    ss += __shfl_xor(ss, 1);
    ss += __shfl_xor(ss, 2);
    float rn = ss > 0.f ? rsqrtf(ss) : 0.f;
    half8 h;
    h[0] = (_Float16)(va[0] * rn); h[1] = (_Float16)(va[1] * rn);
    h[2] = (_Float16)(va[2] * rn); h[3] = (_Float16)(va[3] * rn);
    h[4] = (_Float16)(vb[0] * rn); h[5] = (_Float16)(vb[1] * rn);
    h[6] = (_Float16)(vb[2] * rn); h[7] = (_Float16)(vb[3] * rn);
    __builtin_nontemporal_store(h, reinterpret_cast<half8*>(a.xhat + (size_t)row * 32 + q * 8));
    return;
  }

  if (bid < a.nb_norm + a.nb_pe) {
    // ---- pack p/e slots, all groups ----
    int s = (bid - a.nb_norm) * 256 + tid;
    if (s >= a.slotOff[4]) return;
    if      (s < a.slotOff[1]) pack_pe_one<1, 32>(a.p[0], a.e[0], a.pe[0], s);
    else if (s < a.slotOff[2]) pack_pe_one<2, 32>(a.p[1], a.e[1], a.pe[1], s - a.slotOff[1]);
    else if (s < a.slotOff[3]) pack_pe_one<3, 64>(a.p[2], a.e[2], a.pe[2], s - a.slotOff[2]);
    else                       pack_pe_one<4, 64>(a.p[3], a.e[3], a.pe[3], s - a.slotOff[3]);
    return;
  }

  // ---- pack weights: one block per group ----
  int g = bid - a.nb_norm - a.nb_pe;  // 0..3
  int d = g + 1;
  int PEP = (d <= 2) ? 32 : 64;
  int KD  = 32 * (1 + d) + PEP;
  _Float16* pg = a.psi + (size_t)g * (16 * 224);

  for (int i = tid; i < 16 * KD; i += 256) pg[i] = (_Float16)0.f;
  __syncthreads();

  int k     = tid & 15;
  int piece = tid >> 4;
  int np    = 1 + 3 * d;
  if (piece >= np) return;

  const WPtrs& w = a.w[g];
  const float* src;
  _Float16* dst;
  int len;
  float scale;
  if (piece == 0) {
    src = w.wc + k * 32; dst = pg + k * KD; len = 32; scale = 0.25f;
  } else if (piece <= d) {
    int s = piece - 1;
    src = w.wn + (size_t)(k * d + s) * 32; dst = pg + k * KD + 32 * (1 + s);
    len = 32; scale = 0.25f / d;
  } else if (piece <= 2 * d) {
    int s = piece - 1 - d;
    src = w.wp + (size_t)(k * d + s) * 3;
    dst = pg + k * KD + 32 * (1 + d) + 16 * s;
    len = 3; scale = 0.25f / d;
  } else {
    int s = piece - 1 - 2 * d;
    src = w.we + (size_t)(k * d + s) * 8;
    dst = pg + k * KD + 32 * (1 + d) + 16 * s + 4;
    len = 8; scale = 0.25f / d;
  }
  float ss = 0.f;
  for (int j = 0; j < len; ++j) ss += src[j] * src[j];
  float n  = sqrtf(ss);
  float sc = n > 0.f ? scale / n : 0.f;
  for (int j = 0; j < len; ++j) dst[j] = (_Float16)(src[j] * sc);
}

// ---------------------------------------------------------------------------
// Fused main kernel: gathered MFMA GEMM for all 4 groups, NCH chunks per wave
// for memory-level parallelism. Phases: indices -> A-gathers -> MFMA -> store.
// xhat gathers stay cached (reused ~3.5x); pe reads + out writes nontemporal.
// MFMA 16x16x32 f16:  A row = lane&15, B col = lane&15, k-chunk = lane>>4.
// C/D: col = lane&15, row = (lane>>4)*4 + reg  [verified layout].
// ---------------------------------------------------------------------------
struct MainArgs {
  const _Float16* xhat;
  const _Float16* pe[4];
  const _Float16* psi;       // group g at psi + g*16*224, row stride KD(g)
  const int* sel[4];
  const int* nei[4];
  float* out;
  int nd[4];
  int blkOff[5];             // cumulative block offsets per group
};

template <int D, int PEP, int NCH>
__device__ inline void main_one(const MainArgs& a, int g, int blk) {
  constexpr int NMF  = 1 + D;
  constexpr int PEMF = PEP / 32;
  constexpr int NF   = NMF + PEMF;
  constexpr int KD   = 32 * NF;

  const _Float16* xhat = a.xhat;
  const _Float16* pe   = a.pe[g];
  const _Float16* psi  = a.psi + (size_t)g * (16 * 224);
  const int* sel = a.sel[g];
  const int* nei = a.nei[g];
  int nd = a.nd[g];

  int wave    = threadIdx.x >> 6;
  int lane    = threadIdx.x & 63;
  int nchunks = (nd + 15) >> 4;
  int chunk0  = (blk * 4 + wave) * NCH;
  if (chunk0 >= nchunks) return;
  int r = lane & 15;   // A row / B col / C col
  int c = lane >> 4;   // k-chunk

  // B fragments: loaded once, constant for the whole kernel.
  half8 bx[NF];
  {
    const _Float16* pb = psi + (size_t)r * KD + c * 8;
#pragma unroll
    for (int t = 0; t < NF; ++t)
      bx[t] = *reinterpret_cast<const half8*>(pb + 32 * t);
  }

  // ---- phase 1: indices for all NCH chunks (independent loads) ----
  int riA[NCH];
  int sidx[NCH];
  int gidx[NCH][D];
#pragma unroll
  for (int u = 0; u < NCH; ++u) {
    int chunk = chunk0 + u;
    int ri = (chunk < nchunks) ? (chunk * 16 + r) : 0;
    if (ri > nd - 1) ri = nd - 1;
    riA[u]  = ri;
    sidx[u] = sel[ri];
  }
#pragma unroll
  for (int u = 0; u < NCH; ++u)
#pragma unroll
    for (int s = 0; s < D; ++s)
      gidx[u][s] = nei[(size_t)riA[u] * D + s];

  // ---- phase 2: A fragments for all chunks (independent gathers) ----
  half8 af[NCH][NF];
#pragma unroll
  for (int u = 0; u < NCH; ++u) {
    af[u][0] = *reinterpret_cast<const half8*>(xhat + (size_t)sidx[u] * 32 + c * 8);
#pragma unroll
    for (int s = 0; s < D; ++s)
      af[u][1 + s] = *reinterpret_cast<const half8*>(xhat + (size_t)gidx[u][s] * 32 + c * 8);
#pragma unroll
    for (int m = 0; m < PEMF; ++m)
      af[u][NMF + m] = __builtin_nontemporal_load(
          reinterpret_cast<const half8*>(pe + (size_t)riA[u] * PEP + 32 * m + c * 8));
  }

  // ---- phase 3: MFMAs ----
  floatx4 acc[NCH];
#pragma unroll
  for (int u = 0; u < NCH; ++u) {
    acc[u] = floatx4{0.f, 0.f, 0.f, 0.f};
#pragma unroll
    for (int t = 0; t < NF; ++t)
      acc[u] = __builtin_amdgcn_mfma_f32_16x16x32_f16(af[u][t], bx[t], acc[u], 0, 0, 0);
  }

  // ---- phase 4: writeback (streaming, nontemporal) ----
#pragma unroll
  for (int u = 0; u < NCH; ++u) {
    int chunk = chunk0 + u;
    if (chunk >= nchunks) break;
    int i0 = chunk << 4;
#pragma unroll
    for (int j = 0; j < 4; ++j) {
      int n  = i0 + c * 4 + j;
      int so = __shfl(sidx[u], c * 4 + j);  // sel[i0 + c*4 + j]
      if (n < nd) {
        float* orow = a.out + (size_t)so * 64 + r;
#pragma unroll
        for (int q = 0; q < 4; ++q)
          __builtin_nontemporal_store((q == D - 1) ? acc[u][j] : 0.f, orow + q * 16);
      }
    }
  }
}

__global__ __launch_bounds__(256) void k_main(MainArgs a) {
  int bid = blockIdx.x;
  if (bid < a.blkOff[1])      main_one<1, 32, 6>(a, 0, bid);
  else if (bid < a.blkOff[2]) main_one<2, 32, 5>(a, 1, bid - a.blkOff[1]);
  else if (bid < a.blkOff[3]) main_one<3, 64, 4>(a, 2, bid - a.blkOff[2]);
  else                        main_one<4, 64, 3>(a, 3, bid - a.blkOff[3]);
}

// ---------------------------------------------------------------------------
extern "C" void kernel_launch(void* const* d_in, const int* in_sizes, int n_in,
                              void* d_out, int out_size, void* d_ws, size_t ws_size,
                              hipStream_t stream) {
  const float* x = (const float*)d_in[0];
  int N = in_sizes[0] / 32;

  PrepArgs pa;
  MainArgs ma;
  pa.x = x; pa.N = N;
  int nd[4];
  for (int g = 0; g < 4; ++g) {
    int b = 1 + g * 8;
    ma.sel[g]  = (const int*)d_in[b + 0];
    ma.nei[g]  = (const int*)d_in[b + 1];
    pa.p[g]    = (const float*)d_in[b + 2];
    pa.e[g]    = (const float*)d_in[b + 3];
    pa.w[g].wc = (const float*)d_in[b + 4];
    pa.w[g].wn = (const float*)d_in[b + 5];
    pa.w[g].wp = (const float*)d_in[b + 6];
    pa.w[g].we = (const float*)d_in[b + 7];
    nd[g] = in_sizes[b];
    ma.nd[g] = nd[g];
  }
  ma.out = (float*)d_out;

  // workspace layout
  char* ws = (char*)d_ws;
  auto align256 = [](size_t o) { return (o + 255) & ~(size_t)255; };
  _Float16* xhat = (_Float16*)ws;
  size_t off = (size_t)N * 32 * 2;
  for (int g = 0; g < 4; ++g) {
    off = align256(off);
    pa.pe[g] = (_Float16*)(ws + off);
    ma.pe[g] = pa.pe[g];
    off += (size_t)nd[g] * ((g < 2) ? 32 : 64) * 2;
  }
  off = align256(off);
  _Float16* psi = (_Float16*)(ws + off);
  pa.psi = psi;
  ma.psi = psi;
  pa.xhat = xhat;
  ma.xhat = xhat;

  // prep grid: [norm | pe | 4 weight blocks]
  pa.nb_norm = (N + 63) / 64;
  pa.slotOff[0] = 0;
  for (int g = 0; g < 4; ++g) pa.slotOff[g + 1] = pa.slotOff[g] + nd[g] * (g + 1);
  pa.nb_pe = (pa.slotOff[4] + 255) / 256;
  int prep_blocks = pa.nb_norm + pa.nb_pe + 4;

  // main grid: per-group block counts (4 waves/block, NCH chunks/wave)
  const int NCHg[4] = {6, 5, 4, 3};
  ma.blkOff[0] = 0;
  for (int g = 0; g < 4; ++g) {
    int ch = (nd[g] + 15) / 16;
    int perBlk = 4 * NCHg[g];
    ma.blkOff[g + 1] = ma.blkOff[g] + (ch + perBlk - 1) / perBlk;
  }

  k_prep<<<prep_blocks, 256, 0, stream>>>(pa);
  k_main<<<ma.blkOff[4], 256, 0, stream>>>(ma);
}

// Round 7
// 196.400 us; speedup vs baseline: 1.1726x; 1.1726x over previous
//
#include <hip/hip_runtime.h>
#include <stdint.h>

typedef _Float16 half8 __attribute__((ext_vector_type(8)));
typedef float floatx4 __attribute__((ext_vector_type(4)));
typedef float fvec4 __attribute__((ext_vector_type(4)));

struct WPtrs { const float *wc, *wn, *wp, *we; };

// ---------------------------------------------------------------------------
// Fused prep kernel: grid = [norm blocks | part blocks | 4 weight blocks]
//  - norm: x rows -> unit fp16 xhat
//  - part: per-node fp16 partial score from p/e terms (weights normed in LDS)
//  - weights: Wc+Wn normalized+scaled into psi (fp16, MFMA B layout)
// ---------------------------------------------------------------------------
struct PrepArgs {
  const float* x; _Float16* xhat; int N; int nb_norm;
  const float* p[4]; const float* e[4]; _Float16* part[4];
  int nd[4];
  int pb[5];                 // cumulative part-block offsets (after nb_norm)
  WPtrs w[4]; _Float16* psi;
};

template <int D>
__device__ inline void part_one(const PrepArgs& a, int g, int lblk, int tid,
                                float* wl) {
  const float* __restrict__ p  = a.p[g];
  const float* __restrict__ e  = a.e[g];
  _Float16* __restrict__ part  = a.part[g];
  int nd = a.nd[g];

  // ---- stage normalized weights into LDS: wl[(k*D+s)*11 + j] ----
  if (tid < 16 * D) {
    const float* sp = a.w[g].wp + tid * 3;   // tid = k*D+s
    float a0 = sp[0], a1 = sp[1], a2 = sp[2];
    float n1 = sqrtf(a0 * a0 + a1 * a1 + a2 * a2);
    float s1 = n1 > 0.f ? 0.25f / (D * n1) : 0.f;
    wl[tid * 11 + 0] = a0 * s1;
    wl[tid * 11 + 1] = a1 * s1;
    wl[tid * 11 + 2] = a2 * s1;
    const float* se = a.w[g].we + tid * 8;
    float b0 = se[0], b1 = se[1], b2 = se[2], b3 = se[3];
    float b4 = se[4], b5 = se[5], b6 = se[6], b7 = se[7];
    float n2 = sqrtf(b0 * b0 + b1 * b1 + b2 * b2 + b3 * b3 +
                     b4 * b4 + b5 * b5 + b6 * b6 + b7 * b7);
    float s2 = n2 > 0.f ? 0.25f / (D * n2) : 0.f;
    wl[tid * 11 + 3]  = b0 * s2; wl[tid * 11 + 4]  = b1 * s2;
    wl[tid * 11 + 5]  = b2 * s2; wl[tid * 11 + 6]  = b3 * s2;
    wl[tid * 11 + 7]  = b4 * s2; wl[tid * 11 + 8]  = b5 * s2;
    wl[tid * 11 + 9]  = b6 * s2; wl[tid * 11 + 10] = b7 * s2;
  }
  __syncthreads();

  int node = lblk * 256 + tid;
  if (node >= nd) return;

  // ---- load + normalize this node's p/e slots ----
  float ph[D][3], eh[D][8];
#pragma unroll
  for (int s = 0; s < D; ++s) {
    const float* pp = p + ((size_t)node * D + s) * 3;
    float a0 = pp[0], a1 = pp[1], a2 = pp[2];
    float n1 = sqrtf(a0 * a0 + a1 * a1 + a2 * a2);
    float r1 = n1 > 0.f ? 1.f / n1 : 0.f;
    ph[s][0] = a0 * r1; ph[s][1] = a1 * r1; ph[s][2] = a2 * r1;

    const fvec4* ee = reinterpret_cast<const fvec4*>(e + ((size_t)node * D + s) * 8);
    fvec4 e0 = ee[0], e1 = ee[1];
    float n2 = sqrtf(e0[0] * e0[0] + e0[1] * e0[1] + e0[2] * e0[2] + e0[3] * e0[3] +
                     e1[0] * e1[0] + e1[1] * e1[1] + e1[2] * e1[2] + e1[3] * e1[3]);
    float r2 = n2 > 0.f ? 1.f / n2 : 0.f;
    eh[s][0] = e0[0] * r2; eh[s][1] = e0[1] * r2;
    eh[s][2] = e0[2] * r2; eh[s][3] = e0[3] * r2;
    eh[s][4] = e1[0] * r2; eh[s][5] = e1[1] * r2;
    eh[s][6] = e1[2] * r2; eh[s][7] = e1[3] * r2;
  }

  // ---- 16 partial scores ----
  half8 h0, h1;
#pragma unroll
  for (int k = 0; k < 16; ++k) {
    float t = 0.f;
#pragma unroll
    for (int s = 0; s < D; ++s) {
      const float* w = wl + (k * D + s) * 11;
      t += ph[s][0] * w[0] + ph[s][1] * w[1] + ph[s][2] * w[2];
#pragma unroll
      for (int j = 0; j < 8; ++j) t += eh[s][j] * w[3 + j];
    }
    if (k < 8) h0[k] = (_Float16)t; else h1[k - 8] = (_Float16)t;
  }
  _Float16* dst = part + (size_t)node * 16;
  *reinterpret_cast<half8*>(dst)     = h0;
  *reinterpret_cast<half8*>(dst + 8) = h1;
}

__global__ __launch_bounds__(256) void k_prep(PrepArgs a) {
  __shared__ float wl[16 * 4 * 11];
  int bid = blockIdx.x, tid = threadIdx.x;

  if (bid < a.nb_norm) {
    // ---- normalize x rows: 4 lanes per row ----
    int row = bid * 64 + (tid >> 2);
    int q   = tid & 3;
    if (row >= a.N) return;
    const fvec4* xr = reinterpret_cast<const fvec4*>(a.x + (size_t)row * 32 + q * 8);
    fvec4 va = xr[0];
    fvec4 vb = xr[1];
    float ss = va[0] * va[0] + va[1] * va[1] + va[2] * va[2] + va[3] * va[3] +
               vb[0] * vb[0] + vb[1] * vb[1] + vb[2] * vb[2] + vb[3] * vb[3];
    ss += __shfl_xor(ss, 1);
    ss += __shfl_xor(ss, 2);
    float rn = ss > 0.f ? rsqrtf(ss) : 0.f;
    half8 h;
    h[0] = (_Float16)(va[0] * rn); h[1] = (_Float16)(va[1] * rn);
    h[2] = (_Float16)(va[2] * rn); h[3] = (_Float16)(va[3] * rn);
    h[4] = (_Float16)(vb[0] * rn); h[5] = (_Float16)(vb[1] * rn);
    h[6] = (_Float16)(vb[2] * rn); h[7] = (_Float16)(vb[3] * rn);
    *reinterpret_cast<half8*>(a.xhat + (size_t)row * 32 + q * 8) = h;
    return;
  }

  int b2 = bid - a.nb_norm;
  if (b2 < a.pb[4]) {
    if      (b2 < a.pb[1]) part_one<1>(a, 0, b2,           tid, wl);
    else if (b2 < a.pb[2]) part_one<2>(a, 1, b2 - a.pb[1], tid, wl);
    else if (b2 < a.pb[3]) part_one<3>(a, 2, b2 - a.pb[2], tid, wl);
    else                   part_one<4>(a, 3, b2 - a.pb[3], tid, wl);
    return;
  }

  // ---- pack Wc + Wn into psi: row k = [wc(32) | wn_s(32)*d], fp16 ----
  int g = b2 - a.pb[4];          // 0..3
  int d = g + 1;
  int KD = 32 * (1 + d);
  _Float16* pg = a.psi + (size_t)g * (16 * 160);

  int k     = tid & 15;
  int piece = tid >> 4;
  if (piece > d) return;
  const float* src;
  float scale;
  if (piece == 0) { src = a.w[g].wc + k * 32;                          scale = 0.25f; }
  else            { src = a.w[g].wn + (size_t)(k * d + piece - 1) * 32; scale = 0.25f / d; }
  float ss = 0.f;
  for (int j = 0; j < 32; ++j) ss += src[j] * src[j];
  float n  = sqrtf(ss);
  float sc = n > 0.f ? scale / n : 0.f;
  _Float16* dst = pg + k * KD + 32 * piece;
  for (int j = 0; j < 32; ++j) dst[j] = (_Float16)(src[j] * sc);
}

// ---------------------------------------------------------------------------
// Fused main kernel: gathered MFMA GEMM (x terms only), acc seeded with the
// fp16 p/e partial. NCH chunks per wave for memory-level parallelism.
// MFMA 16x16x32 f16:  A row = lane&15, B col = lane&15, k-chunk = lane>>4.
// C/D: col = lane&15, row = (lane>>4)*4 + reg  [verified layout].
// ---------------------------------------------------------------------------
struct MainArgs {
  const _Float16* xhat;
  const _Float16* part[4];
  const _Float16* psi;       // group g at psi + g*16*160, row stride KD(g)
  const int* sel[4];
  const int* nei[4];
  float* out;
  int nd[4];
  int blkOff[5];             // cumulative block offsets per group
};

template <int D, int NCH>
__device__ inline void main_one(const MainArgs& a, int g, int blk) {
  constexpr int NF = 1 + D;
  constexpr int KD = 32 * NF;

  const _Float16* xhat = a.xhat;
  const _Float16* part = a.part[g];
  const _Float16* psi  = a.psi + (size_t)g * (16 * 160);
  const int* sel = a.sel[g];
  const int* nei = a.nei[g];
  int nd = a.nd[g];

  int wave    = threadIdx.x >> 6;
  int lane    = threadIdx.x & 63;
  int nchunks = (nd + 15) >> 4;
  int chunk0  = (blk * 4 + wave) * NCH;
  if (chunk0 >= nchunks) return;
  int r = lane & 15;   // A row / B col / C col
  int c = lane >> 4;   // k-chunk

  // B fragments: loaded once, constant for the whole kernel.
  half8 bx[NF];
  {
    const _Float16* pb = psi + (size_t)r * KD + c * 8;
#pragma unroll
    for (int t = 0; t < NF; ++t)
      bx[t] = *reinterpret_cast<const half8*>(pb + 32 * t);
  }

  // ---- phase 1: indices for all NCH chunks (independent loads) ----
  int riA[NCH];
  int sidx[NCH];
  int gidx[NCH][D];
#pragma unroll
  for (int u = 0; u < NCH; ++u) {
    int chunk = chunk0 + u;
    int ri = (chunk < nchunks) ? (chunk * 16 + r) : 0;
    if (ri > nd - 1) ri = nd - 1;
    riA[u]  = ri;
    sidx[u] = sel[ri];
  }
#pragma unroll
  for (int u = 0; u < NCH; ++u)
#pragma unroll
    for (int s = 0; s < D; ++s)
      gidx[u][s] = nei[(size_t)riA[u] * D + s];

  // ---- phase 2: acc seed from partial + A-fragment gathers ----
  floatx4 acc[NCH];
#pragma unroll
  for (int u = 0; u < NCH; ++u) {
    int i0 = (chunk0 + u) << 4;
#pragma unroll
    for (int j = 0; j < 4; ++j) {
      int n = i0 + c * 4 + j;
      if (n > nd - 1) n = nd - 1;
      acc[u][j] = (float)part[(size_t)n * 16 + r];
    }
  }

  half8 af[NCH][NF];
#pragma unroll
  for (int u = 0; u < NCH; ++u) {
    af[u][0] = *reinterpret_cast<const half8*>(xhat + (size_t)sidx[u] * 32 + c * 8);
#pragma unroll
    for (int s = 0; s < D; ++s)
      af[u][1 + s] = *reinterpret_cast<const half8*>(xhat + (size_t)gidx[u][s] * 32 + c * 8);
  }

  // ---- phase 3: MFMAs ----
#pragma unroll
  for (int u = 0; u < NCH; ++u)
#pragma unroll
    for (int t = 0; t < NF; ++t)
      acc[u] = __builtin_amdgcn_mfma_f32_16x16x32_f16(af[u][t], bx[t], acc[u], 0, 0, 0);

  // ---- phase 4: writeback ----
#pragma unroll
  for (int u = 0; u < NCH; ++u) {
    int chunk = chunk0 + u;
    if (chunk >= nchunks) break;
    int i0 = chunk << 4;
#pragma unroll
    for (int j = 0; j < 4; ++j) {
      int n  = i0 + c * 4 + j;
      int so = __shfl(sidx[u], c * 4 + j);  // sel[i0 + c*4 + j]
      if (n < nd) {
        float* orow = a.out + (size_t)so * 64 + r;
#pragma unroll
        for (int q = 0; q < 4; ++q)
          orow[q * 16] = (q == D - 1) ? acc[u][j] : 0.f;
      }
    }
  }
}

__global__ __launch_bounds__(256) void k_main(MainArgs a) {
  int bid = blockIdx.x;
  if (bid < a.blkOff[1])      main_one<1, 6>(a, 0, bid);
  else if (bid < a.blkOff[2]) main_one<2, 5>(a, 1, bid - a.blkOff[1]);
  else if (bid < a.blkOff[3]) main_one<3, 4>(a, 2, bid - a.blkOff[2]);
  else                        main_one<4, 3>(a, 3, bid - a.blkOff[3]);
}

// ---------------------------------------------------------------------------
extern "C" void kernel_launch(void* const* d_in, const int* in_sizes, int n_in,
                              void* d_out, int out_size, void* d_ws, size_t ws_size,
                              hipStream_t stream) {
  const float* x = (const float*)d_in[0];
  int N = in_sizes[0] / 32;

  PrepArgs pa;
  MainArgs ma;
  pa.x = x; pa.N = N;
  int nd[4];
  for (int g = 0; g < 4; ++g) {
    int b = 1 + g * 8;
    ma.sel[g]  = (const int*)d_in[b + 0];
    ma.nei[g]  = (const int*)d_in[b + 1];
    pa.p[g]    = (const float*)d_in[b + 2];
    pa.e[g]    = (const float*)d_in[b + 3];
    pa.w[g].wc = (const float*)d_in[b + 4];
    pa.w[g].wn = (const float*)d_in[b + 5];
    pa.w[g].wp = (const float*)d_in[b + 6];
    pa.w[g].we = (const float*)d_in[b + 7];
    nd[g] = in_sizes[b];
    pa.nd[g] = nd[g];
    ma.nd[g] = nd[g];
  }
  ma.out = (float*)d_out;

  // workspace layout: xhat | part[4] | psi
  char* ws = (char*)d_ws;
  auto align256 = [](size_t o) { return (o + 255) & ~(size_t)255; };
  _Float16* xhat = (_Float16*)ws;
  size_t off = (size_t)N * 32 * 2;
  for (int g = 0; g < 4; ++g) {
    off = align256(off);
    pa.part[g] = (_Float16*)(ws + off);
    ma.part[g] = pa.part[g];
    off += (size_t)nd[g] * 16 * 2;
  }
  off = align256(off);
  _Float16* psi = (_Float16*)(ws + off);
  pa.psi = psi;
  ma.psi = psi;
  pa.xhat = xhat;
  ma.xhat = xhat;

  // prep grid: [norm | part | 4 weight blocks]
  pa.nb_norm = (N + 63) / 64;
  pa.pb[0] = 0;
  for (int g = 0; g < 4; ++g) pa.pb[g + 1] = pa.pb[g] + (nd[g] + 255) / 256;
  int prep_blocks = pa.nb_norm + pa.pb[4] + 4;

  // main grid: per-group block counts (4 waves/block, NCH chunks/wave)
  const int NCHg[4] = {6, 5, 4, 3};
  ma.blkOff[0] = 0;
  for (int g = 0; g < 4; ++g) {
    int ch = (nd[g] + 15) / 16;
    int perBlk = 4 * NCHg[g];
    ma.blkOff[g + 1] = ma.blkOff[g] + (ch + perBlk - 1) / perBlk;
  }

  k_prep<<<prep_blocks, 256, 0, stream>>>(pa);
  k_main<<<ma.blkOff[4], 256, 0, stream>>>(ma);
}